// Round 6
// baseline (219.193 us; speedup 1.0000x reference)
//
#include <hip/hip_runtime.h>
#include <stdint.h>

#define B_ 4
#define S_ 2048
#define D_ 1024
#define H_ 16
#define DH_ 64
#define M_TOT (B_*S_)   // 8192
#define N1_ (3*D_)      // 3072
#define K_ D_           // 1024

typedef __bf16 bf16_8 __attribute__((ext_vector_type(8)));
typedef float  f32x4  __attribute__((ext_vector_type(4)));
typedef unsigned short u16;

typedef __attribute__((address_space(1))) const void* gas_t;
typedef __attribute__((address_space(3))) void*       las_t;

__device__ __forceinline__ unsigned short f2bf(float f) {
    union { float f; unsigned u; } v; v.f = f;
    unsigned r = v.u + 0x7FFFu + ((v.u >> 16) & 1u);
    return (unsigned short)(r >> 16);
}

__device__ __forceinline__ void async_ld16(const void* g, void* l) {
    __builtin_amdgcn_global_load_lds((gas_t)g, (las_t)l, 16, 0, 0);
}

// ---------------- cast fp32 -> bf16 (X, W1, W2) ----------------
__global__ __launch_bounds__(256)
void cast_kernel(const float* __restrict__ X, const float* __restrict__ W1,
                 const float* __restrict__ W2, unsigned short* __restrict__ Xb,
                 unsigned short* __restrict__ W1b, unsigned short* __restrict__ W2b) {
    const int nX  = (M_TOT * K_) / 4;   // 2097152
    const int nW1 = (N1_ * K_) / 4;     // 786432
    int i = blockIdx.x * 256 + threadIdx.x;   // float4 index
    const float4* src; unsigned short* dst; int j;
    if (i < nX)            { src = (const float4*)X;  dst = Xb;  j = i; }
    else if (i < nX + nW1) { src = (const float4*)W1; dst = W1b; j = i - nX; }
    else                   { src = (const float4*)W2; dst = W2b; j = i - nX - nW1; }
    float4 v = src[j];
    ushort4 o;
    o.x = f2bf(v.x); o.y = f2bf(v.y); o.z = f2bf(v.z); o.w = f2bf(v.w);
    ((ushort4*)dst)[j] = o;
}

// ---------------- gemm_bt: C[M,N] = A[M,K] * B[N,K]^T + bias ----------------
// Round-0 proven structure: 128x128 tile, 4 waves (2x2), BK=64,
// global_load_lds width 16, XOR-swizzled LDS (0 bank conflicts), XCD swizzle.
// EPI: 0 = fp32 C[M,N]   (GEMM2)
//      2 = QKV split: Q,K written TRANSPOSED to QT/KT[B,H,64,S], V compact
//          Vb[B,S,1024]. (Round-5 verified: GEMM1 68.6us, faster than plain.)
template<int N, int NBX, int EPI>
__global__ __launch_bounds__(256)
void gemm_bt(const unsigned short* __restrict__ A,
             const unsigned short* __restrict__ Bm,
             const float* __restrict__ bias,
             void* __restrict__ C, int K,
             u16* __restrict__ QT, u16* __restrict__ KT, u16* __restrict__ Vb) {
    __shared__ unsigned short As[128 * 64];
    __shared__ unsigned short Bs[128 * 64];
    const int t    = threadIdx.x;
    const int wid  = t >> 6;
    const int lane = t & 63;
    const int lrow = lane & 15;
    const int lq   = lane >> 4;

    const int lid  = blockIdx.y * NBX + blockIdx.x;
    const int xcd  = lid & 7;
    const int slot = lid >> 3;
    const int by   = xcd * (gridDim.y >> 3) + slot / NBX;
    const int bx   = slot % NBX;
    const int m0   = by * 128;
    const int n0   = bx * 128;

    const int wm   = (wid >> 1) * 64;
    const int wn   = (wid & 1) * 64;

    f32x4 acc[4][4] = {};

    for (int k0 = 0; k0 < K; k0 += 64) {
#pragma unroll
        for (int p = 0; p < 4; p++) {
            const int c   = p * 256 + t;          // chunk 0..1023
            const int row = c >> 3;
            const int kb  = (c & 7) ^ (row & 7);  // un-swizzled global k-block
            async_ld16(A  + (size_t)(m0 + row) * K + k0 + kb * 8, (char*)As + c * 16);
            async_ld16(Bm + (size_t)(n0 + row) * K + k0 + kb * 8, (char*)Bs + c * 16);
        }
        __syncthreads();

#pragma unroll
        for (int ks = 0; ks < 2; ks++) {
            bf16_8 af[4], bfr[4];
#pragma unroll
            for (int mt = 0; mt < 4; mt++) {
                const int r  = wm + mt * 16 + lrow;
                const int kb = (ks * 4 + lq) ^ (r & 7);
                af[mt] = *(const bf16_8*)(As + (r * 8 + kb) * 8);
            }
#pragma unroll
            for (int nt = 0; nt < 4; nt++) {
                const int r  = wn + nt * 16 + lrow;
                const int kb = (ks * 4 + lq) ^ (r & 7);
                bfr[nt] = *(const bf16_8*)(Bs + (r * 8 + kb) * 8);
            }
#pragma unroll
            for (int mt = 0; mt < 4; mt++)
#pragma unroll
                for (int nt = 0; nt < 4; nt++)
                    acc[mt][nt] = __builtin_amdgcn_mfma_f32_16x16x32_bf16(af[mt], bfr[nt], acc[mt][nt], 0, 0, 0);
        }
        __syncthreads();
    }

    // epilogue: C row = m0+wm+mt*16+lq*4+i, col = n0+wn+nt*16+lrow
#pragma unroll
    for (int nt = 0; nt < 4; nt++) {
        const int col = n0 + wn + nt * 16 + lrow;
        const float bv = bias[col];
#pragma unroll
        for (int mt = 0; mt < 4; mt++) {
            const int row = m0 + wm + mt * 16 + lq * 4;
            f32x4 a = acc[mt][nt];
            if constexpr (EPI == 2) {
                ushort4 o;
                o.x = f2bf(a[0] + bv); o.y = f2bf(a[1] + bv);
                o.z = f2bf(a[2] + bv); o.w = f2bf(a[3] + bv);
                const int b = row >> 11, s = row & 2047;
                const int d = col & 63;
                if (col < 1024) {
                    *(ushort4*)(QT + ((size_t)(b * 16 + (col >> 6)) * 64 + d) * (size_t)S_ + s) = o;
                } else if (col < 2048) {
                    *(ushort4*)(KT + ((size_t)(b * 16 + ((col >> 6) - 16)) * 64 + d) * (size_t)S_ + s) = o;
                } else {
                    u16* vp = Vb + ((size_t)b * S_ + s) * (size_t)D_ + (col - 2048);
                    vp[0]      = o.x;
                    vp[D_]     = o.y;
                    vp[2 * D_] = o.z;
                    vp[3 * D_] = o.w;
                }
            } else {
                float* Cp = (float*)C;
#pragma unroll
                for (int i = 0; i < 4; i++)
                    Cp[(size_t)(row + i) * N + col] = a[i] + bv;
            }
        }
    }
}

// ---------------- attention: ONE kernel per head (QK^T + softmax + PV) -------
// grid = 64 (b,h); 512 threads = 8 waves.
// Phase 1: wave w computes 64x64 QK^T partial over s in [w*256, w*256+256)
//          (verified scores_t MFMA/output mapping), stores to LDS Sp[w]
//          (row stride 68 floats to spread banks).
// Phase 2: 512 threads reduce the 8 partials + softmax (same math/order as
//          the previous attn_softmax -> bit-identical), w -> LDS Ws (bf16).
// Phase 3: wave w computes O[b,h,d,s] for its 256-s slice (verified fused PV
//          fragment code), V read once from compact Vb.
// Removes the Scp global round-trip (8MB wr + 64MB redundant rd), one launch,
// and all cross-block QK redundancy. LDS: 8*64*68*4 + 64*72*2 = 148480 B.
__global__ __launch_bounds__(512)
void attn_head(const u16* __restrict__ QT, const u16* __restrict__ KT,
               const u16* __restrict__ Vb, u16* __restrict__ O) {
    __shared__ float Sp[8][64 * 68];
    __shared__ u16   Ws[64 * 72];
    const int bh = blockIdx.x;
    const int b = bh >> 4, h = bh & 15;
    const int t = threadIdx.x, wid = t >> 6, lane = t & 63;
    const int lrow = lane & 15, lq = lane >> 4;

    const u16* Qh = QT + (size_t)bh * 64 * S_;
    const u16* Kh = KT + (size_t)bh * 64 * S_;

    // ---- phase 1: QK^T partial for this wave's s-chunk
    {
        f32x4 acc[4][4] = {};
        const int sbeg = wid * 256;
#pragma unroll 2
        for (int s0 = sbeg; s0 < sbeg + 256; s0 += 32) {
            const int so = s0 + lq * 8;
            bf16_8 aq[4], bk[4];
#pragma unroll
            for (int mt = 0; mt < 4; mt++)
                aq[mt] = *(const bf16_8*)(Qh + (mt * 16 + lrow) * S_ + so);
#pragma unroll
            for (int nt = 0; nt < 4; nt++)
                bk[nt] = *(const bf16_8*)(Kh + (nt * 16 + lrow) * S_ + so);
#pragma unroll
            for (int mt = 0; mt < 4; mt++)
#pragma unroll
                for (int nt = 0; nt < 4; nt++)
                    acc[mt][nt] = __builtin_amdgcn_mfma_f32_16x16x32_bf16(aq[mt], bk[nt], acc[mt][nt], 0, 0, 0);
        }
        float* myp = &Sp[wid][0];
#pragma unroll
        for (int mt = 0; mt < 4; mt++)
#pragma unroll
            for (int nt = 0; nt < 4; nt++)
#pragma unroll
                for (int i = 0; i < 4; i++)
                    myp[(mt * 16 + lq * 4 + i) * 68 + nt * 16 + lrow] = acc[mt][nt][i];
    }
    __syncthreads();

    // ---- phase 2: reduce 8 partials + softmax -> Ws
    {
        const int d = t >> 3, q = t & 7;   // thread owns row d, e-cols q*8..q*8+7
        float s[8] = {};
#pragma unroll
        for (int c = 0; c < 8; c++) {
            const float* p = &Sp[c][d * 68 + q * 8];
#pragma unroll
            for (int j = 0; j < 8; j++) s[j] += p[j];
        }
        const float scale = 0.022097086912079608f;  // 1/sqrt(2048)
        float m = -3.0e38f;
#pragma unroll
        for (int i = 0; i < 8; i++) { s[i] *= scale; m = fmaxf(m, s[i]); }
        m = fmaxf(m, __shfl_xor(m, 1));
        m = fmaxf(m, __shfl_xor(m, 2));
        m = fmaxf(m, __shfl_xor(m, 4));
        float sum = 0.f;
#pragma unroll
        for (int i = 0; i < 8; i++) { s[i] = __expf(s[i] - m); sum += s[i]; }
        sum += __shfl_xor(sum, 1);
        sum += __shfl_xor(sum, 2);
        sum += __shfl_xor(sum, 4);
        const float inv = 1.0f / sum;
        u16* w = Ws + d * 72 + q * 8;
#pragma unroll
        for (int i = 0; i < 8; i++) w[i] = f2bf(s[i] * inv);
    }
    __syncthreads();

    // ---- phase 3: PV for this wave's 256-s slice
    bf16_8 aw[4][2];
#pragma unroll
    for (int mt = 0; mt < 4; mt++)
#pragma unroll
        for (int ks = 0; ks < 2; ks++)
            aw[mt][ks] = *(const bf16_8*)(Ws + (mt * 16 + lrow) * 72 + ks * 32 + lq * 8);

    const size_t vbase = (size_t)b * S_ * D_;
    const int voff = h * 64;
    const size_t obase = (size_t)b * (H_ * DH_ * S_) + (size_t)h * (DH_ * S_);
#pragma unroll
    for (int sb = 0; sb < 4; sb++) {
        const int s0 = wid * 256 + sb * 64;
        f32x4 o[4][4] = {};
#pragma unroll
        for (int ks = 0; ks < 2; ks++) {
            bf16_8 bv[4];
#pragma unroll
            for (int nt = 0; nt < 4; nt++)
                bv[nt] = *(const bf16_8*)(Vb + vbase + (size_t)(s0 + nt * 16 + lrow) * D_ + voff + ks * 32 + lq * 8);
#pragma unroll
            for (int mt = 0; mt < 4; mt++)
#pragma unroll
                for (int nt = 0; nt < 4; nt++)
                    o[mt][nt] = __builtin_amdgcn_mfma_f32_16x16x32_bf16(aw[mt][ks], bv[nt], o[mt][nt], 0, 0, 0);
        }
#pragma unroll
        for (int mt = 0; mt < 4; mt++)
#pragma unroll
            for (int nt = 0; nt < 4; nt++) {
                const int d = mt * 16 + lq * 4;
                const int s = s0 + nt * 16 + lrow;
#pragma unroll
                for (int i = 0; i < 4; i++)
                    O[obase + (size_t)(d + i) * S_ + s] = f2bf(o[mt][nt][i]);
            }
    }
}

extern "C" void kernel_launch(void* const* d_in, const int* in_sizes, int n_in,
                              void* d_out, int out_size, void* d_ws, size_t ws_size,
                              hipStream_t stream) {
    const float* X  = (const float*)d_in[0];
    const float* W1 = (const float*)d_in[1];
    const float* b1 = (const float*)d_in[2];
    const float* W2 = (const float*)d_in[3];
    const float* b2 = (const float*)d_in[4];

    char* ws = (char*)d_ws;
    unsigned short* Xb  = (unsigned short*)(ws + 0);                 // 16 MB, dead after GEMM1
    unsigned short* W1b = (unsigned short*)(ws + (16u << 20));       // 6 MB, dead after GEMM1
    unsigned short* W2b = (unsigned short*)(ws + (22u << 20));       // 2 MB
    unsigned short* QT  = (unsigned short*)(ws + (24u << 20));       // 16 MB  Q^T [B,H,64,S]
    unsigned short* KT  = (unsigned short*)(ws + (40u << 20));       // 16 MB  K^T [B,H,64,S]
    unsigned short* Vb  = (unsigned short*)(ws + (56u << 20));       // 16 MB  V   [B,S,1024]
    // after GEMM1, [0,22MB) is free:
    unsigned short* Ob  = (unsigned short*)(ws + (1u << 20));        // 16 MB attention output

    cast_kernel<<<12288, 256, 0, stream>>>(X, W1, W2, Xb, W1b, W2b);
    gemm_bt<N1_, N1_/128, 2><<<dim3(N1_ / 128, M_TOT / 128), 256, 0, stream>>>(
        Xb, W1b, b1, nullptr, K_, QT, KT, Vb);
    attn_head<<<64, 512, 0, stream>>>(QT, KT, Vb, Ob);
    gemm_bt<D_, D_/128, 0><<<dim3(D_ / 128, M_TOT / 128), 256, 0, stream>>>(
        Ob, W2b, b2, d_out, K_, nullptr, nullptr, nullptr);
}

// Round 7
// 217.157 us; speedup vs baseline: 1.0094x; 1.0094x over previous
//
#include <hip/hip_runtime.h>
#include <stdint.h>

#define B_ 4
#define S_ 2048
#define D_ 1024
#define H_ 16
#define DH_ 64
#define M_TOT (B_*S_)   // 8192
#define N1_ (3*D_)      // 3072
#define K_ D_           // 1024
#define NCH 8           // s-chunks for attention score partials

typedef __bf16 bf16_8 __attribute__((ext_vector_type(8)));
typedef float  f32x4  __attribute__((ext_vector_type(4)));
typedef unsigned short u16;

typedef __attribute__((address_space(1))) const void* gas_t;
typedef __attribute__((address_space(3))) void*       las_t;

__device__ __forceinline__ unsigned short f2bf(float f) {
    union { float f; unsigned u; } v; v.f = f;
    unsigned r = v.u + 0x7FFFu + ((v.u >> 16) & 1u);
    return (unsigned short)(r >> 16);
}

__device__ __forceinline__ void async_ld16(const void* g, void* l) {
    __builtin_amdgcn_global_load_lds((gas_t)g, (las_t)l, 16, 0, 0);
}

// ---------------- cast fp32 -> bf16 (X, W1, W2) ----------------
__global__ __launch_bounds__(256)
void cast_kernel(const float* __restrict__ X, const float* __restrict__ W1,
                 const float* __restrict__ W2, unsigned short* __restrict__ Xb,
                 unsigned short* __restrict__ W1b, unsigned short* __restrict__ W2b) {
    const int nX  = (M_TOT * K_) / 4;   // 2097152
    const int nW1 = (N1_ * K_) / 4;     // 786432
    int i = blockIdx.x * 256 + threadIdx.x;   // float4 index
    const float4* src; unsigned short* dst; int j;
    if (i < nX)            { src = (const float4*)X;  dst = Xb;  j = i; }
    else if (i < nX + nW1) { src = (const float4*)W1; dst = W1b; j = i - nX; }
    else                   { src = (const float4*)W2; dst = W2b; j = i - nX - nW1; }
    float4 v = src[j];
    ushort4 o;
    o.x = f2bf(v.x); o.y = f2bf(v.y); o.z = f2bf(v.z); o.w = f2bf(v.w);
    ((ushort4*)dst)[j] = o;
}

// ---------------- gemm_bt: C[M,N] = A[M,K] * B[N,K]^T (+ bias) ----------------
// Proven 128x128 / 4-wave / BK=64 structure (global_load_lds w16, XOR swizzle,
// XCD swizzle).
// EPI 2: GEMM1. Q,K,V all written TRANSPOSED: QT/KT/VT[B,H,64,S] (coalesced
//        ushort4 stores along s). bias = b1.
// EPI 3: G_heavy: A rows remapped from VT: global row r = i*1024 + (h*64+e),
//        i = b*2+shi; A[r][k] = VT[(b*16+h)*64+e][shi*1024+k]. Output VW^T
//        bf16 at VWT[((i*16+h)*1024+n)*64+e] (e-contig rows for G_light's
//        B-fragments). No bias. Computes VW[r][n] = sum_k V[..]*W2[n,k].
template<int N, int NBX, int EPI>
__global__ __launch_bounds__(256)
void gemm_bt(const unsigned short* __restrict__ A,
             const unsigned short* __restrict__ Bm,
             const float* __restrict__ bias,
             void* __restrict__ C, int K,
             u16* __restrict__ QT, u16* __restrict__ KT, u16* __restrict__ VT) {
    __shared__ unsigned short As[128 * 64];
    __shared__ unsigned short Bs[128 * 64];
    const int t    = threadIdx.x;
    const int wid  = t >> 6;
    const int lane = t & 63;
    const int lrow = lane & 15;
    const int lq   = lane >> 4;

    const int lid  = blockIdx.y * NBX + blockIdx.x;
    const int xcd  = lid & 7;
    const int slot = lid >> 3;
    const int by   = xcd * (gridDim.y >> 3) + slot / NBX;
    const int bx   = slot % NBX;
    const int m0   = by * 128;
    const int n0   = bx * 128;

    // EPI 3 A-row mapping constants (constant per block: 128 | 1024)
    const int inst  = by >> 3;          // i = b*2+shi
    const int hblk  = by & 7;           // 128-row block within the 1024-row instance
    const size_t arow0 = (size_t)((inst >> 1) * 1024 + hblk * 128);
    const int koff  = (inst & 1) * 1024;

    const int wm   = (wid >> 1) * 64;
    const int wn   = (wid & 1) * 64;

    f32x4 acc[4][4] = {};

    for (int k0 = 0; k0 < K; k0 += 64) {
#pragma unroll
        for (int p = 0; p < 4; p++) {
            const int c   = p * 256 + t;          // chunk 0..1023
            const int row = c >> 3;
            const int kb  = (c & 7) ^ (row & 7);  // un-swizzled global k-block
            if constexpr (EPI == 3)
                async_ld16(A + (arow0 + row) * (size_t)S_ + koff + k0 + kb * 8, (char*)As + c * 16);
            else
                async_ld16(A + (size_t)(m0 + row) * K + k0 + kb * 8, (char*)As + c * 16);
            async_ld16(Bm + (size_t)(n0 + row) * K + k0 + kb * 8, (char*)Bs + c * 16);
        }
        __syncthreads();

#pragma unroll
        for (int ks = 0; ks < 2; ks++) {
            bf16_8 af[4], bfr[4];
#pragma unroll
            for (int mt = 0; mt < 4; mt++) {
                const int r  = wm + mt * 16 + lrow;
                const int kb = (ks * 4 + lq) ^ (r & 7);
                af[mt] = *(const bf16_8*)(As + (r * 8 + kb) * 8);
            }
#pragma unroll
            for (int nt = 0; nt < 4; nt++) {
                const int r  = wn + nt * 16 + lrow;
                const int kb = (ks * 4 + lq) ^ (r & 7);
                bfr[nt] = *(const bf16_8*)(Bs + (r * 8 + kb) * 8);
            }
#pragma unroll
            for (int mt = 0; mt < 4; mt++)
#pragma unroll
                for (int nt = 0; nt < 4; nt++)
                    acc[mt][nt] = __builtin_amdgcn_mfma_f32_16x16x32_bf16(af[mt], bfr[nt], acc[mt][nt], 0, 0, 0);
        }
        __syncthreads();
    }

    // epilogue: C row = m0+wm+mt*16+lq*4+i, col = n0+wn+nt*16+lrow
#pragma unroll
    for (int nt = 0; nt < 4; nt++) {
        const int col = n0 + wn + nt * 16 + lrow;
        const float bv = (EPI == 2) ? bias[col] : 0.f;
#pragma unroll
        for (int mt = 0; mt < 4; mt++) {
            const int row = m0 + wm + mt * 16 + lq * 4;
            f32x4 a = acc[mt][nt];
            if constexpr (EPI == 2) {
                ushort4 o;
                o.x = f2bf(a[0] + bv); o.y = f2bf(a[1] + bv);
                o.z = f2bf(a[2] + bv); o.w = f2bf(a[3] + bv);
                const int b = row >> 11, s = row & 2047;
                const int d = col & 63;
                if (col < 1024) {
                    *(ushort4*)(QT + ((size_t)(b * 16 + (col >> 6)) * 64 + d) * (size_t)S_ + s) = o;
                } else if (col < 2048) {
                    *(ushort4*)(KT + ((size_t)(b * 16 + ((col >> 6) - 16)) * 64 + d) * (size_t)S_ + s) = o;
                } else {
                    *(ushort4*)(VT + ((size_t)(b * 16 + ((col >> 6) - 32)) * 64 + d) * (size_t)S_ + s) = o;
                }
            } else {  // EPI == 3: VW^T store, e = row&63 (4 consecutive -> ushort4)
                ushort4 o;
                o.x = f2bf(a[0]); o.y = f2bf(a[1]); o.z = f2bf(a[2]); o.w = f2bf(a[3]);
                u16* Cp = (u16*)C;
                *(ushort4*)(Cp + ((size_t)((row >> 10) * 16 + ((row >> 6) & 15)) * 1024 + col) * 64
                                + (row & 63)) = o;
            }
        }
    }
}

// ---------------- attn_qk: per-head scores via staged batched GEMM -----------
// grid (bh=64, ch=8), 256 thr / 4 waves (2x2 over 32x32 of the 64x64 tile).
// partial[d][e] = sum_{s in chunk} QT[d][s]*KT[e][s]. Q/K staged coalesced
// via global_load_lds (rows are s-contiguous in QT/KT) -> each element read
// exactly ONCE chip-wide (no redundancy, no strided fragment loads).
__global__ __launch_bounds__(256)
void attn_qk(const u16* __restrict__ QT, const u16* __restrict__ KT,
             float* __restrict__ Scp) {
    __shared__ u16 Qs[64 * 64];
    __shared__ u16 Ks[64 * 64];
    const int bh = blockIdx.x, ch = blockIdx.y;
    const int t = threadIdx.x, wid = t >> 6, lane = t & 63;
    const int lrow = lane & 15, lq = lane >> 4;
    const int wm2 = (wid >> 1) * 32, wn2 = (wid & 1) * 32;
    const u16* Qh = QT + (size_t)bh * 64 * S_;
    const u16* Kh = KT + (size_t)bh * 64 * S_;

    f32x4 acc[2][2] = {};
    for (int kt = 0; kt < 4; kt++) {
        const int s0 = ch * 256 + kt * 64;
#pragma unroll
        for (int p = 0; p < 4; p++) {
            const int c   = p * 256 + t;          // 0..1023: 0..511 Q, 512..1023 K
            const int cc  = c & 511;
            const int row = cc >> 3;
            const int kb  = (cc & 7) ^ (row & 7);
            if (p < 2)
                async_ld16(Qh + (size_t)row * S_ + s0 + kb * 8, (char*)Qs + cc * 16);
            else
                async_ld16(Kh + (size_t)row * S_ + s0 + kb * 8, (char*)Ks + cc * 16);
        }
        __syncthreads();
#pragma unroll
        for (int ks = 0; ks < 2; ks++) {
            bf16_8 aq[2], bk[2];
#pragma unroll
            for (int mt = 0; mt < 2; mt++) {
                const int r  = wm2 + mt * 16 + lrow;
                const int kb = (ks * 4 + lq) ^ (r & 7);
                aq[mt] = *(const bf16_8*)(Qs + (r * 8 + kb) * 8);
            }
#pragma unroll
            for (int nt = 0; nt < 2; nt++) {
                const int r  = wn2 + nt * 16 + lrow;
                const int kb = (ks * 4 + lq) ^ (r & 7);
                bk[nt] = *(const bf16_8*)(Ks + (r * 8 + kb) * 8);
            }
#pragma unroll
            for (int mt = 0; mt < 2; mt++)
#pragma unroll
                for (int nt = 0; nt < 2; nt++)
                    acc[mt][nt] = __builtin_amdgcn_mfma_f32_16x16x32_bf16(aq[mt], bk[nt], acc[mt][nt], 0, 0, 0);
        }
        __syncthreads();
    }

    float* out = Scp + (size_t)(bh * NCH + ch) * 4096;
#pragma unroll
    for (int mt = 0; mt < 2; mt++)
#pragma unroll
        for (int nt = 0; nt < 2; nt++)
#pragma unroll
            for (int i = 0; i < 4; i++)
                out[(wm2 + mt * 16 + lq * 4 + i) * 64 + wn2 + nt * 16 + lrow] = acc[mt][nt][i];
}

// ---------------- attn_softmax: reduce partials + softmax (verified) ---------
__global__ __launch_bounds__(256)
void attn_softmax(const float* __restrict__ Scp, unsigned short* __restrict__ Wb) {
    const int bh = blockIdx.x;
    const int t = threadIdx.x;
    const int d = t >> 2, q = t & 3;
    float s[16] = {};
#pragma unroll
    for (int c = 0; c < NCH; c++) {
        const float4* p = (const float4*)(Scp + ((size_t)(bh * NCH + c) * 64 + d) * 64 + q * 16);
#pragma unroll
        for (int j = 0; j < 4; j++) {
            float4 v = p[j];
            s[j*4+0] += v.x; s[j*4+1] += v.y; s[j*4+2] += v.z; s[j*4+3] += v.w;
        }
    }
    const float scale = 0.022097086912079608f;  // 1/sqrt(2048)
    float m = -3.0e38f;
#pragma unroll
    for (int i = 0; i < 16; i++) { s[i] *= scale; m = fmaxf(m, s[i]); }
    m = fmaxf(m, __shfl_xor(m, 1));
    m = fmaxf(m, __shfl_xor(m, 2));
    float sum = 0.f;
#pragma unroll
    for (int i = 0; i < 16; i++) { s[i] = __expf(s[i] - m); sum += s[i]; }
    sum += __shfl_xor(sum, 1);
    sum += __shfl_xor(sum, 2);
    const float inv = 1.0f / sum;
    unsigned short* w = Wb + (size_t)bh * 4096 + d * 64 + q * 16;
    ushort4 o0, o1, o2, o3;
    o0.x=f2bf(s[0]*inv);  o0.y=f2bf(s[1]*inv);  o0.z=f2bf(s[2]*inv);  o0.w=f2bf(s[3]*inv);
    o1.x=f2bf(s[4]*inv);  o1.y=f2bf(s[5]*inv);  o1.z=f2bf(s[6]*inv);  o1.w=f2bf(s[7]*inv);
    o2.x=f2bf(s[8]*inv);  o2.y=f2bf(s[9]*inv);  o2.z=f2bf(s[10]*inv); o2.w=f2bf(s[11]*inv);
    o3.x=f2bf(s[12]*inv); o3.y=f2bf(s[13]*inv); o3.z=f2bf(s[14]*inv); o3.w=f2bf(s[15]*inv);
    ((ushort4*)w)[0]=o0; ((ushort4*)w)[1]=o1; ((ushort4*)w)[2]=o2; ((ushort4*)w)[3]=o3;
}

// ---------------- gemm_light: out[b,s',n] = sum_e w[d,e]*VWT[..][e,n] + b2 ----
// grid (nb=8, byy=64): byy = (b,h); 128 out-rows s' = m0 + 2d + shi, m0=byy*128.
// K=64 single-shot: stage w head (8KB) + VWT slices shi=0/1 rows n0..n0+127
// (32KB) via global_load_lds, one MFMA pass (32/wave), fp32 store + bias.
// Waves 2x2 over (shi, n-half). VWT read exactly once chip-wide.
__global__ __launch_bounds__(256)
void gemm_light(const u16* __restrict__ Wb, const u16* __restrict__ VWT,
                const float* __restrict__ b2, float* __restrict__ out) {
    __shared__ u16 Ws[64 * 64];     // 8 KB: w rows d, 64 e (128B, 8x16B swizzled)
    __shared__ u16 Vs[256 * 64];    // 32 KB: [slice 2][n-row 128][e 64]
    const int bx = blockIdx.x, byy = blockIdx.y;
    const int n0 = bx * 128;
    const int b = byy >> 4, h = byy & 15;
    const int t = threadIdx.x, wid = t >> 6, lane = t & 63;
    const int lrow = lane & 15, lq = lane >> 4;
    const int wsl = wid >> 1;       // slice (shi)
    const int wn  = wid & 1;        // n half

#pragma unroll
    for (int j = 0; j < 2; j++) {
        const int c = j * 256 + t;                // 512 chunks of w
        const int row = c >> 3, kb = (c & 7) ^ (row & 7);
        async_ld16(Wb + (size_t)byy * 4096 + row * 64 + kb * 8, (char*)Ws + c * 16);
    }
#pragma unroll
    for (int p = 0; p < 8; p++) {
        const int c = p * 256 + t;                // 2048 chunks of VWT
        const int slice = c >> 10, rowc = (c >> 3) & 127;
        const int kb = (c & 7) ^ (rowc & 7);
        async_ld16(VWT + ((size_t)((b * 2 + slice) * 16 + h) * 1024 + n0 + rowc) * 64 + kb * 8,
                   (char*)Vs + c * 16);
    }
    __syncthreads();

    f32x4 acc[4][4] = {};
#pragma unroll
    for (int ks = 0; ks < 2; ks++) {
        bf16_8 af[4], bfr[4];
#pragma unroll
        for (int mt = 0; mt < 4; mt++) {
            const int r  = mt * 16 + lrow;
            const int kb = (ks * 4 + lq) ^ (r & 7);
            af[mt] = *(const bf16_8*)(Ws + (r * 8 + kb) * 8);
        }
#pragma unroll
        for (int nt = 0; nt < 4; nt++) {
            const int rn = wn * 64 + nt * 16 + lrow;
            const int kb = (ks * 4 + lq) ^ (rn & 7);
            bfr[nt] = *(const bf16_8*)(Vs + ((wsl * 128 + rn) * 8 + kb) * 8);
        }
#pragma unroll
        for (int mt = 0; mt < 4; mt++)
#pragma unroll
            for (int nt = 0; nt < 4; nt++)
                acc[mt][nt] = __builtin_amdgcn_mfma_f32_16x16x32_bf16(af[mt], bfr[nt], acc[mt][nt], 0, 0, 0);
    }

    float* op = out + (size_t)byy * 128 * 1024;   // rows m0 = byy*128
#pragma unroll
    for (int nt = 0; nt < 4; nt++) {
        const int col = n0 + wn * 64 + nt * 16 + lrow;
        const float bv = b2[col];
#pragma unroll
        for (int mt = 0; mt < 4; mt++)
#pragma unroll
            for (int i = 0; i < 4; i++) {
                const int d = mt * 16 + lq * 4 + i;
                op[(size_t)(2 * d + wsl) * 1024 + col] = acc[mt][nt][i] + bv;
            }
    }
}

extern "C" void kernel_launch(void* const* d_in, const int* in_sizes, int n_in,
                              void* d_out, int out_size, void* d_ws, size_t ws_size,
                              hipStream_t stream) {
    const float* X  = (const float*)d_in[0];
    const float* W1 = (const float*)d_in[1];
    const float* b1 = (const float*)d_in[2];
    const float* W2 = (const float*)d_in[3];
    const float* b2 = (const float*)d_in[4];

    char* ws = (char*)d_ws;
    unsigned short* Xb  = (unsigned short*)(ws + 0);                 // 16 MB, dead after G1
    unsigned short* W1b = (unsigned short*)(ws + (16u << 20));       // 6 MB, dead after G1
    unsigned short* W2b = (unsigned short*)(ws + (22u << 20));       // 2 MB, live thru G_heavy
    unsigned short* QT  = (unsigned short*)(ws + (24u << 20));       // 16 MB  Q^T [B,H,64,S]
    unsigned short* KT  = (unsigned short*)(ws + (40u << 20));       // 16 MB  K^T [B,H,64,S]
    unsigned short* VT  = (unsigned short*)(ws + (56u << 20));       // 16 MB  V^T [B,H,64,S]
    // after G1, [0,22MB) is free:
    unsigned short* Wb  = (unsigned short*)(ws + 0);                 // 512 KB softmaxed w
    unsigned short* VWT = (unsigned short*)(ws + (1u << 20));        // 16 MB  VW^T bf16
    // d_out (32 MB fp32) is dead until gemm_light -> 8 MB for score partials
    float* Scp = (float*)d_out;

    cast_kernel<<<12288, 256, 0, stream>>>(X, W1, W2, Xb, W1b, W2b);
    gemm_bt<N1_, N1_/128, 2><<<dim3(N1_ / 128, M_TOT / 128), 256, 0, stream>>>(
        Xb, W1b, b1, nullptr, K_, QT, KT, VT);
    attn_qk<<<dim3(64, NCH), 256, 0, stream>>>(QT, KT, Scp);
    attn_softmax<<<64, 256, 0, stream>>>(Scp, Wb);
    gemm_bt<D_, D_/128, 3><<<dim3(D_ / 128, M_TOT / 128), 256, 0, stream>>>(
        VT, W2b, b2, VWT, K_, nullptr, nullptr, nullptr);
    gemm_light<<<dim3(8, 64), 256, 0, stream>>>(Wb, VWT, b2, (float*)d_out);
}

// Round 8
// 200.009 us; speedup vs baseline: 1.0959x; 1.0857x over previous
//
#include <hip/hip_runtime.h>
#include <stdint.h>

#define B_ 4
#define S_ 2048
#define D_ 1024
#define H_ 16
#define DH_ 64
#define M_TOT (B_*S_)   // 8192
#define N1_ (3*D_)      // 3072
#define K_ D_           // 1024
#define NCH 8           // s-chunks for attention score partials

typedef __bf16 bf16_8 __attribute__((ext_vector_type(8)));
typedef float  f32x4  __attribute__((ext_vector_type(4)));
typedef unsigned short u16;

typedef __attribute__((address_space(1))) const void* gas_t;
typedef __attribute__((address_space(3))) void*       las_t;

__device__ __forceinline__ unsigned short f2bf(float f) {
    union { float f; unsigned u; } v; v.f = f;
    unsigned r = v.u + 0x7FFFu + ((v.u >> 16) & 1u);
    return (unsigned short)(r >> 16);
}

__device__ __forceinline__ void async_ld16(const void* g, void* l) {
    __builtin_amdgcn_global_load_lds((gas_t)g, (las_t)l, 16, 0, 0);
}

// ---------------- cast fp32 -> bf16 (X, W1, W2) ----------------
__global__ __launch_bounds__(256)
void cast_kernel(const float* __restrict__ X, const float* __restrict__ W1,
                 const float* __restrict__ W2, unsigned short* __restrict__ Xb,
                 unsigned short* __restrict__ W1b, unsigned short* __restrict__ W2b) {
    const int nX  = (M_TOT * K_) / 4;   // 2097152
    const int nW1 = (N1_ * K_) / 4;     // 786432
    int i = blockIdx.x * 256 + threadIdx.x;   // float4 index
    const float4* src; unsigned short* dst; int j;
    if (i < nX)            { src = (const float4*)X;  dst = Xb;  j = i; }
    else if (i < nX + nW1) { src = (const float4*)W1; dst = W1b; j = i - nX; }
    else                   { src = (const float4*)W2; dst = W2b; j = i - nX - nW1; }
    float4 v = src[j];
    ushort4 o;
    o.x = f2bf(v.x); o.y = f2bf(v.y); o.z = f2bf(v.z); o.w = f2bf(v.w);
    ((ushort4*)dst)[j] = o;
}

// ---------------- gemm_bt: C[M,N] = A[M,K] * B[N,K]^T + bias ----------------
// Round-0 proven structure: 128x128 tile, 4 waves (2x2), BK=64,
// global_load_lds width 16, XOR-swizzled LDS (0 bank conflicts), XCD swizzle.
// EPI: 0 = fp32 C[M,N]   (GEMM2)
//      2 = QKV split: Q,K written TRANSPOSED to QT/KT[B,H,64,S] (contiguous
//          ushort4 stores along s), V to compact Vb[B,S,1024].
//          (Round-5 measured: 68.6us, FETCH 71MB — the best G1 variant.
//           Round-7's all-transposed VT variant regressed to 78.9/84MB; keep Vb.)
template<int N, int NBX, int EPI>
__global__ __launch_bounds__(256)
void gemm_bt(const unsigned short* __restrict__ A,
             const unsigned short* __restrict__ Bm,
             const float* __restrict__ bias,
             void* __restrict__ C, int K,
             u16* __restrict__ QT, u16* __restrict__ KT, u16* __restrict__ Vb) {
    __shared__ unsigned short As[128 * 64];
    __shared__ unsigned short Bs[128 * 64];
    const int t    = threadIdx.x;
    const int wid  = t >> 6;
    const int lane = t & 63;
    const int lrow = lane & 15;
    const int lq   = lane >> 4;

    const int lid  = blockIdx.y * NBX + blockIdx.x;
    const int xcd  = lid & 7;
    const int slot = lid >> 3;
    const int by   = xcd * (gridDim.y >> 3) + slot / NBX;
    const int bx   = slot % NBX;
    const int m0   = by * 128;
    const int n0   = bx * 128;

    const int wm   = (wid >> 1) * 64;
    const int wn   = (wid & 1) * 64;

    f32x4 acc[4][4] = {};

    for (int k0 = 0; k0 < K; k0 += 64) {
#pragma unroll
        for (int p = 0; p < 4; p++) {
            const int c   = p * 256 + t;          // chunk 0..1023
            const int row = c >> 3;
            const int kb  = (c & 7) ^ (row & 7);  // un-swizzled global k-block
            async_ld16(A  + (size_t)(m0 + row) * K + k0 + kb * 8, (char*)As + c * 16);
            async_ld16(Bm + (size_t)(n0 + row) * K + k0 + kb * 8, (char*)Bs + c * 16);
        }
        __syncthreads();

#pragma unroll
        for (int ks = 0; ks < 2; ks++) {
            bf16_8 af[4], bfr[4];
#pragma unroll
            for (int mt = 0; mt < 4; mt++) {
                const int r  = wm + mt * 16 + lrow;
                const int kb = (ks * 4 + lq) ^ (r & 7);
                af[mt] = *(const bf16_8*)(As + (r * 8 + kb) * 8);
            }
#pragma unroll
            for (int nt = 0; nt < 4; nt++) {
                const int r  = wn + nt * 16 + lrow;
                const int kb = (ks * 4 + lq) ^ (r & 7);
                bfr[nt] = *(const bf16_8*)(Bs + (r * 8 + kb) * 8);
            }
#pragma unroll
            for (int mt = 0; mt < 4; mt++)
#pragma unroll
                for (int nt = 0; nt < 4; nt++)
                    acc[mt][nt] = __builtin_amdgcn_mfma_f32_16x16x32_bf16(af[mt], bfr[nt], acc[mt][nt], 0, 0, 0);
        }
        __syncthreads();
    }

    // epilogue: C row = m0+wm+mt*16+lq*4+i, col = n0+wn+nt*16+lrow
#pragma unroll
    for (int nt = 0; nt < 4; nt++) {
        const int col = n0 + wn + nt * 16 + lrow;
        const float bv = bias[col];
#pragma unroll
        for (int mt = 0; mt < 4; mt++) {
            const int row = m0 + wm + mt * 16 + lq * 4;
            f32x4 a = acc[mt][nt];
            if constexpr (EPI == 2) {
                ushort4 o;
                o.x = f2bf(a[0] + bv); o.y = f2bf(a[1] + bv);
                o.z = f2bf(a[2] + bv); o.w = f2bf(a[3] + bv);
                const int b = row >> 11, s = row & 2047;
                const int d = col & 63;
                if (col < 1024) {
                    *(ushort4*)(QT + ((size_t)(b * 16 + (col >> 6)) * 64 + d) * (size_t)S_ + s) = o;
                } else if (col < 2048) {
                    *(ushort4*)(KT + ((size_t)(b * 16 + ((col >> 6) - 16)) * 64 + d) * (size_t)S_ + s) = o;
                } else {
                    u16* vp = Vb + ((size_t)b * S_ + s) * (size_t)D_ + (col - 2048);
                    vp[0]      = o.x;
                    vp[D_]     = o.y;
                    vp[2 * D_] = o.z;
                    vp[3 * D_] = o.w;
                }
            } else {
                float* Cp = (float*)C;
#pragma unroll
                for (int i = 0; i < 4; i++)
                    Cp[(size_t)(row + i) * N + col] = a[i] + bv;
            }
        }
    }
}

// ---------------- attn_qk: per-head scores via staged batched GEMM -----------
// grid (bh=64, ch=8), 256 thr / 4 waves (2x2 over 32x32 of the 64x64 tile).
// partial[d][e] = sum_{s in chunk} QT[d][s]*KT[e][s]. Q/K staged coalesced
// via global_load_lds (rows are s-contiguous in QT/KT) -> each element read
// exactly ONCE chip-wide. Replaces round-5's attn_scores_t whose direct
// 4KB-strided fragment loads were the ~40us pool (round-7 proven correct).
// Scp layout and fp32 K-accumulation order identical to scores_t.
__global__ __launch_bounds__(256)
void attn_qk(const u16* __restrict__ QT, const u16* __restrict__ KT,
             float* __restrict__ Scp) {
    __shared__ u16 Qs[64 * 64];
    __shared__ u16 Ks[64 * 64];
    const int bh = blockIdx.x, ch = blockIdx.y;
    const int t = threadIdx.x, wid = t >> 6, lane = t & 63;
    const int lrow = lane & 15, lq = lane >> 4;
    const int wm2 = (wid >> 1) * 32, wn2 = (wid & 1) * 32;
    const u16* Qh = QT + (size_t)bh * 64 * S_;
    const u16* Kh = KT + (size_t)bh * 64 * S_;

    f32x4 acc[2][2] = {};
    for (int kt = 0; kt < 4; kt++) {
        const int s0 = ch * 256 + kt * 64;
#pragma unroll
        for (int p = 0; p < 4; p++) {
            const int c   = p * 256 + t;          // 0..1023: 0..511 Q, 512..1023 K
            const int cc  = c & 511;
            const int row = cc >> 3;
            const int kb  = (cc & 7) ^ (row & 7);
            if (p < 2)
                async_ld16(Qh + (size_t)row * S_ + s0 + kb * 8, (char*)Qs + cc * 16);
            else
                async_ld16(Kh + (size_t)row * S_ + s0 + kb * 8, (char*)Ks + cc * 16);
        }
        __syncthreads();
#pragma unroll
        for (int ks = 0; ks < 2; ks++) {
            bf16_8 aq[2], bk[2];
#pragma unroll
            for (int mt = 0; mt < 2; mt++) {
                const int r  = wm2 + mt * 16 + lrow;
                const int kb = (ks * 4 + lq) ^ (r & 7);
                aq[mt] = *(const bf16_8*)(Qs + (r * 8 + kb) * 8);
            }
#pragma unroll
            for (int nt = 0; nt < 2; nt++) {
                const int r  = wn2 + nt * 16 + lrow;
                const int kb = (ks * 4 + lq) ^ (r & 7);
                bk[nt] = *(const bf16_8*)(Ks + (r * 8 + kb) * 8);
            }
#pragma unroll
            for (int mt = 0; mt < 2; mt++)
#pragma unroll
                for (int nt = 0; nt < 2; nt++)
                    acc[mt][nt] = __builtin_amdgcn_mfma_f32_16x16x32_bf16(aq[mt], bk[nt], acc[mt][nt], 0, 0, 0);
        }
        __syncthreads();
    }

    float* out = Scp + (size_t)(bh * NCH + ch) * 4096;
#pragma unroll
    for (int mt = 0; mt < 2; mt++)
#pragma unroll
        for (int nt = 0; nt < 2; nt++)
#pragma unroll
            for (int i = 0; i < 4; i++)
                out[(wm2 + mt * 16 + lq * 4 + i) * 64 + wn2 + nt * 16 + lrow] = acc[mt][nt][i];
}

// ---------------- attention, stage 2 (fused): reduce + softmax + O = w @ V^T ----
// grid (bh=64, sc=8). Each block redundantly reduces its head's 8 score
// partials, softmaxes in-register (deterministic -> all sc-blocks agree),
// writes w to LDS, computes its 256-column slice of O[b,h,d,s].
// V read from compact Vb[B,S,1024]. (Round-3/5 proven.)
__global__ __launch_bounds__(256)
void attn_out_fused(const unsigned short* __restrict__ Vb,
                    const float* __restrict__ Scp,
                    unsigned short* __restrict__ O) {
    __shared__ unsigned short Ws[64 * 72];
    const int bh = blockIdx.x, sc = blockIdx.y;
    const int b = bh >> 4, h = bh & 15;
    const size_t vbase = (size_t)b * S_ * D_;
    const int voff = h * 64;
    const int t = threadIdx.x, wid = t >> 6, lane = t & 63;
    const int lrow = lane & 15, lq = lane >> 4;

    {
        const int d = t >> 2, q = t & 3;
        float s[16] = {};
#pragma unroll
        for (int c = 0; c < NCH; c++) {
            const float4* p = (const float4*)(Scp + ((size_t)(bh * NCH + c) * 64 + d) * 64 + q * 16);
#pragma unroll
            for (int j = 0; j < 4; j++) {
                float4 v = p[j];
                s[j*4+0] += v.x; s[j*4+1] += v.y; s[j*4+2] += v.z; s[j*4+3] += v.w;
            }
        }
        const float scale = 0.022097086912079608f;  // 1/sqrt(2048)
        float m = -3.0e38f;
#pragma unroll
        for (int i = 0; i < 16; i++) { s[i] *= scale; m = fmaxf(m, s[i]); }
        m = fmaxf(m, __shfl_xor(m, 1));   // 4-lane group = one row d
        m = fmaxf(m, __shfl_xor(m, 2));
        float sum = 0.f;
#pragma unroll
        for (int i = 0; i < 16; i++) { s[i] = __expf(s[i] - m); sum += s[i]; }
        sum += __shfl_xor(sum, 1);
        sum += __shfl_xor(sum, 2);
        const float inv = 1.0f / sum;
        unsigned short* w = Ws + d * 72 + q * 16;
#pragma unroll
        for (int i = 0; i < 16; i++) w[i] = f2bf(s[i] * inv);
    }
    __syncthreads();

    bf16_8 aw[4][2];
#pragma unroll
    for (int mt = 0; mt < 4; mt++)
#pragma unroll
        for (int ks = 0; ks < 2; ks++)
            aw[mt][ks] = *(const bf16_8*)(Ws + (mt * 16 + lrow) * 72 + ks * 32 + lq * 8);

    const size_t obase = (size_t)b * (H_ * DH_ * S_) + (size_t)h * (DH_ * S_);
    const int s0 = sc * 256 + wid * 64;
    f32x4 o[4][4] = {};
#pragma unroll
    for (int ks = 0; ks < 2; ks++) {
        bf16_8 bv[4];
#pragma unroll
        for (int nt = 0; nt < 4; nt++)
            bv[nt] = *(const bf16_8*)(Vb + vbase + (size_t)(s0 + nt * 16 + lrow) * D_ + voff + ks * 32 + lq * 8);
#pragma unroll
        for (int mt = 0; mt < 4; mt++)
#pragma unroll
            for (int nt = 0; nt < 4; nt++)
                o[mt][nt] = __builtin_amdgcn_mfma_f32_16x16x32_bf16(aw[mt][ks], bv[nt], o[mt][nt], 0, 0, 0);
    }
#pragma unroll
    for (int mt = 0; mt < 4; mt++)
#pragma unroll
        for (int nt = 0; nt < 4; nt++) {
            const int d = mt * 16 + lq * 4;
            const int s = s0 + nt * 16 + lrow;
#pragma unroll
            for (int i = 0; i < 4; i++)
                O[obase + (size_t)(d + i) * S_ + s] = f2bf(o[mt][nt][i]);
        }
}

extern "C" void kernel_launch(void* const* d_in, const int* in_sizes, int n_in,
                              void* d_out, int out_size, void* d_ws, size_t ws_size,
                              hipStream_t stream) {
    const float* X  = (const float*)d_in[0];
    const float* W1 = (const float*)d_in[1];
    const float* b1 = (const float*)d_in[2];
    const float* W2 = (const float*)d_in[3];
    const float* b2 = (const float*)d_in[4];

    char* ws = (char*)d_ws;
    unsigned short* Xb  = (unsigned short*)(ws + 0);                 // 16 MB, dead after GEMM1
    unsigned short* W1b = (unsigned short*)(ws + (16u << 20));       // 6 MB, dead after GEMM1
    unsigned short* W2b = (unsigned short*)(ws + (22u << 20));       // 2 MB
    unsigned short* QT  = (unsigned short*)(ws + (24u << 20));       // 16 MB  Q^T [B,H,64,S]
    unsigned short* KT  = (unsigned short*)(ws + (40u << 20));       // 16 MB  K^T [B,H,64,S]
    unsigned short* Vb  = (unsigned short*)(ws + (56u << 20));       // 16 MB  V   [B,S,1024]
    // after GEMM1, [0,22MB) is free:
    unsigned short* Ob  = (unsigned short*)(ws + (1u << 20));        // 16 MB attention output
    // d_out (32 MB fp32) is dead until GEMM2 -> use 8 MB of it for score partials
    float* Scp = (float*)d_out;

    cast_kernel<<<12288, 256, 0, stream>>>(X, W1, W2, Xb, W1b, W2b);
    gemm_bt<N1_, N1_/128, 2><<<dim3(N1_ / 128, M_TOT / 128), 256, 0, stream>>>(
        Xb, W1b, b1, nullptr, K_, QT, KT, Vb);
    attn_qk<<<dim3(64, NCH), 256, 0, stream>>>(QT, KT, Scp);
    attn_out_fused<<<dim3(64, NCH), 256, 0, stream>>>(Vb, Scp, Ob);
    gemm_bt<D_, D_/128, 0><<<dim3(D_ / 128, M_TOT / 128), 256, 0, stream>>>(
        Ob, W2b, b2, d_out, K_, nullptr, nullptr, nullptr);
}